// Round 4
// baseline (366.255 us; speedup 1.0000x reference)
//
#include <hip/hip_runtime.h>
#include <cmath>

typedef __bf16 bf16x8 __attribute__((ext_vector_type(8)));
typedef float f32x4 __attribute__((ext_vector_type(4)));
typedef unsigned short u16;
typedef unsigned int u32;

__device__ __forceinline__ u16 f2bf(float f) {
  union { float f; unsigned int u; } v; v.f = f;
  unsigned int u = v.u;
  return (u16)((u + 0x7FFFu + ((u >> 16) & 1u)) >> 16);
}

__device__ __forceinline__ float geluf(float x) {
  return 0.5f * x * (1.0f + erff(x * 0.7071067811865475f));
}

// async global->LDS, 16B per lane. LDS dest = wave-uniform base + lane*16.
__device__ __forceinline__ void gl_lds16(const void* g, void* l) {
  __builtin_amdgcn_global_load_lds(
      (const __attribute__((address_space(1))) u32*)g,
      (__attribute__((address_space(3))) u32*)l, 16, 0, 0);
}

// ---------------- elementwise f32 -> bf16 (8 elems/thread) ----------------
__global__ __launch_bounds__(256) void cvt_bf16(const float* __restrict__ in,
                                                u16* __restrict__ out, int n8) {
  int i = blockIdx.x * 256 + threadIdx.x;
  if (i >= n8) return;
  const float4* p = (const float4*)in + 2 * (size_t)i;
  float4 a = p[0], b = p[1];
  uint4 o;
  o.x = (unsigned)f2bf(a.x) | ((unsigned)f2bf(a.y) << 16);
  o.y = (unsigned)f2bf(a.z) | ((unsigned)f2bf(a.w) << 16);
  o.z = (unsigned)f2bf(b.x) | ((unsigned)f2bf(b.y) << 16);
  o.w = (unsigned)f2bf(b.z) | ((unsigned)f2bf(b.w) << 16);
  ((uint4*)out)[i] = o;
}

// ---------- LDS-tiled transpose + cvt: in (R x C) f32 -> out (C x R) bf16 ----------
__global__ __launch_bounds__(256) void transpose_cvt(const float* __restrict__ in,
                                                     u16* __restrict__ out,
                                                     int R, int C) {
  __shared__ float tile[64][65];
  const int t = threadIdx.x;
  const int c0 = blockIdx.x * 64, r0 = blockIdx.y * 64;
  const int lr = t >> 6, lc = t & 63;
#pragma unroll
  for (int p = 0; p < 16; ++p) {
    int r = p * 4 + lr;
    float v = 0.f;
    if (r0 + r < R && c0 + lc < C) v = in[(size_t)(r0 + r) * C + c0 + lc];
    tile[r][lc] = v;
  }
  __syncthreads();
#pragma unroll
  for (int p = 0; p < 16; ++p) {
    int c = p * 4 + lr;
    if (c0 + c < C && r0 + lc < R)
      out[(size_t)(c0 + c) * R + r0 + lc] = f2bf(tile[lc][c]);
  }
}

// ---------------- bf16 MFMA GEMM: Cpart[z] = A(MxK) * Bt(NxK)^T over K-chunk z --------
template <int WR, int WC>
__global__ __launch_bounds__(256, 3) void gemm_bt(const u16* __restrict__ A,
                                                  const u16* __restrict__ Bt,
                                                  float* __restrict__ Cpart,
                                                  int M, int N, int K, int kPer) {
  constexpr int BM = WR * 64, BN = WC * 64;
  __shared__ __attribute__((aligned(16))) u16 As[BM * 64];
  __shared__ __attribute__((aligned(16))) u16 Bs[BN * 64];
  const int tid = threadIdx.x, wid = tid >> 6, lane = tid & 63;
  const int l16 = lane & 15, quad = lane >> 4;
  const int wm = (wid % WR) * 64, wn = (wid / WR) * 64;
  const int m0 = blockIdx.y * BM, n0 = blockIdx.x * BN;
  const int kIters = K >> 6;
  const int kStart = blockIdx.z * kPer;
  const int kEnd = (kStart + kPer < kIters) ? (kStart + kPer) : kIters;

  const int lrow = lane >> 3;
  const int swz = (lane & 7) ^ lrow;
  const u16* gAb = A + (size_t)m0 * K + (size_t)swz * 8;
  const u16* gBb = Bt + (size_t)n0 * K + (size_t)swz * 8;
  const int sx = l16 & 7;

  f32x4 acc[4][4] = {};
  for (int kt = kStart; kt < kEnd; ++kt) {
    __syncthreads();
    const u16* gA = gAb + (size_t)kt * 64;
    const u16* gB = gBb + (size_t)kt * 64;
#pragma unroll
    for (int j = 0; j < BM / 32; ++j) {
      int i = wid * (BM / 32) + j;
      gl_lds16(gA + (size_t)(i * 8 + lrow) * K, &As[i * 512]);
    }
#pragma unroll
    for (int j = 0; j < BN / 32; ++j) {
      int i = wid * (BN / 32) + j;
      gl_lds16(gB + (size_t)(i * 8 + lrow) * K, &Bs[i * 512]);
    }
    __syncthreads();
    bf16x8 af[4][2], bfr[4][2];
#pragma unroll
    for (int mt = 0; mt < 4; ++mt)
#pragma unroll
      for (int ks = 0; ks < 2; ++ks)
        af[mt][ks] = *(const bf16x8*)(&As[(wm + mt * 16 + l16) * 64 +
                                          (((ks * 4 + quad) ^ sx) * 8)]);
#pragma unroll
    for (int nt = 0; nt < 4; ++nt)
#pragma unroll
      for (int ks = 0; ks < 2; ++ks)
        bfr[nt][ks] = *(const bf16x8*)(&Bs[(wn + nt * 16 + l16) * 64 +
                                           (((ks * 4 + quad) ^ sx) * 8)]);
#pragma unroll
    for (int mt = 0; mt < 4; ++mt)
#pragma unroll
      for (int nt = 0; nt < 4; ++nt)
#pragma unroll
        for (int ks = 0; ks < 2; ++ks)
          acc[mt][nt] = __builtin_amdgcn_mfma_f32_16x16x32_bf16(
              af[mt][ks], bfr[nt][ks], acc[mt][nt], 0, 0, 0);
  }

  float* C = Cpart + (size_t)blockIdx.z * M * N;
#pragma unroll
  for (int mt = 0; mt < 4; ++mt)
#pragma unroll
    for (int nt = 0; nt < 4; ++nt)
#pragma unroll
      for (int r = 0; r < 4; ++r) {
        int row = m0 + wm + mt * 16 + quad * 4 + r;
        int col = n0 + wn + nt * 16 + l16;
        C[(size_t)row * N + col] = acc[mt][nt][r];
      }
}

// ---------------- reduce kernels (split-K epilogues) ----------------
__global__ __launch_bounds__(256) void reduce_gelu(float* __restrict__ base, int P,
                                                   int n4, u16* __restrict__ gout) {
  int i = blockIdx.x * 256 + threadIdx.x;
  if (i >= n4) return;
  size_t n = (size_t)n4 * 4;
  float4 v = ((const float4*)base)[i];
  for (int p = 1; p < P; ++p) {
    float4 w = ((const float4*)(base + (size_t)p * n))[i];
    v.x += w.x; v.y += w.y; v.z += w.z; v.w += w.w;
  }
  if (P > 1) ((float4*)base)[i] = v;
  uint2 o;
  o.x = (u32)f2bf(geluf(v.x)) | ((u32)f2bf(geluf(v.y)) << 16);
  o.y = (u32)f2bf(geluf(v.z)) | ((u32)f2bf(geluf(v.w)) << 16);
  ((uint2*)gout)[i] = o;
}

__global__ __launch_bounds__(256) void reduce_add(const float* __restrict__ base, int P,
                                                  int n4, float* __restrict__ dst) {
  int i = blockIdx.x * 256 + threadIdx.x;
  if (i >= n4) return;
  size_t n = (size_t)n4 * 4;
  float4 v = ((const float4*)base)[i];
  for (int p = 1; p < P; ++p) {
    float4 w = ((const float4*)(base + (size_t)p * n))[i];
    v.x += w.x; v.y += w.y; v.z += w.z; v.w += w.w;
  }
  ((float4*)dst)[i] = v;
}

__global__ __launch_bounds__(256) void reduce_tanh(const float* __restrict__ base, int P,
                                                   int n, float* __restrict__ tokq,
                                                   float* __restrict__ tokv) {
  int i = blockIdx.x * 256 + threadIdx.x;
  if (i >= n) return;
  float v = base[i];
  for (int p = 1; p < P; ++p) v += base[(size_t)p * n + i];
  float t = tanhf(v);
  int col = i & 63, row = i >> 6;
  if (col < 32) tokq[row * 32 + col] = t;
  else          tokv[row * 32 + (col - 32)] = t;
}

// ---------------- prep: tau scaling + RoPE + layouts for attention ----------------
// Q is pre-scaled by 0.125*log2(e) so flash softmax runs in exp2 domain.
#define QSCALE 0.18033688011112042f
__global__ __launch_bounds__(256) void prep_qkv(const float* __restrict__ qkv,
                                                const float* __restrict__ tokq,
                                                const float* __restrict__ tokv,
                                                const float* __restrict__ alpha,
                                                const float* __restrict__ cosb,
                                                const float* __restrict__ sinb,
                                                const int* __restrict__ pos_ids,
                                                u16* __restrict__ Qb,
                                                u16* __restrict__ Kb,
                                                u16* __restrict__ Vt,
                                                u16* __restrict__ Vb) {
  const int s = blockIdx.x;
  const int tid = threadIdx.x;
  __shared__ float cs[16], sn[16], tq_s[32], tv_s[32];
  if (tid < 16) { cs[tid] = cosb[s * 16 + tid]; sn[tid] = sinb[s * 16 + tid]; }
  if (tid < 32) {
    float p = (float)pos_ids[s] + 1.0f;
    float sig = 1.0f / (1.0f + __expf(-alpha[tid] * logf(p)));
    float taupos = 0.5f + sig;
    tq_s[tid] = (tokq[s * 32 + tid] + taupos) * QSCALE;
    tv_s[tid] = tokv[s * 32 + tid] + taupos;
  }
  __syncthreads();
  const float* row = qkv + (size_t)s * 3072;

  for (int idx = tid; idx < 2048; idx += 256) {
    int h = idx >> 6, d = idx & 63;
    float tq = tq_s[h];
    float v;
    if (d < 32) {
      int i = d >> 1;
      float xr = row[h * 64 + i] * tq, xi = row[h * 64 + 16 + i] * tq;
      v = (d & 1) ? (xr * sn[i] + xi * cs[i]) : (xr * cs[i] - xi * sn[i]);
    } else v = row[h * 64 + d] * tq;
    Qb[((size_t)h * 2048 + s) * 64 + d] = f2bf(v);
  }
  for (int idx = tid; idx < 512; idx += 256) {
    int h = idx >> 6, d = idx & 63;
    const float* kr = row + 2048;
    float v;
    if (d < 32) {
      int i = d >> 1;
      float xr = kr[h * 64 + i], xi = kr[h * 64 + 16 + i];
      v = (d & 1) ? (xr * sn[i] + xi * cs[i]) : (xr * cs[i] - xi * sn[i]);
    } else v = kr[h * 64 + d];
    Kb[((size_t)h * 2048 + s) * 64 + d] = f2bf(v);
  }
  for (int idx = tid; idx < 512; idx += 256) {
    int h = idx >> 6, d = idx & 63;
    float v = row[2560 + h * 64 + d] * tv_s[h];
    u16 b = f2bf(v);
    if (Vb) Vb[((size_t)h * 2048 + s) * 64 + d] = b;
    else    Vt[((size_t)h * 64 + d) * 2048 + s] = b;
  }
}

// ---------------- bf16 transpose Vb[h][s][d] -> Vt[h][d][s] ----------------
__global__ __launch_bounds__(256) void vtrans(const u16* __restrict__ Vb,
                                              u16* __restrict__ Vt) {
  __shared__ u16 t[64][68];
  const int s0 = blockIdx.x * 64, h = blockIdx.y;
  const int tid = threadIdx.x;
  const u16* src = Vb + ((size_t)h * 2048 + s0) * 64;
#pragma unroll
  for (int p = 0; p < 4; ++p) {
    int v = p * 256 + tid;
    int r = v >> 4, c = (v & 15) * 4;
    uint2 w = *(const uint2*)(src + (size_t)r * 64 + c);
    t[r][c] = (u16)(w.x & 0xffff); t[r][c + 1] = (u16)(w.x >> 16);
    t[r][c + 2] = (u16)(w.y & 0xffff); t[r][c + 3] = (u16)(w.y >> 16);
  }
  __syncthreads();
  u16* dst = Vt + (size_t)h * 64 * 2048 + s0;
#pragma unroll
  for (int p = 0; p < 4; ++p) {
    int v = p * 256 + tid;
    int d = v >> 4, s = (v & 15) * 4;
    uint2 w;
    w.x = (u32)t[s][d] | ((u32)t[s + 1][d] << 16);
    w.y = (u32)t[s + 2][d] | ((u32)t[s + 3][d] << 16);
    *(uint2*)(dst + (size_t)d * 2048 + s) = w;
  }
}

// ---------------- flash attention v3: KV-split (flash-decoding) ----------------
// grid (40, 32): x enumerates (qb, chunk) pairs, y = head. Each block processes
// up to 8 K-tiles (512 kv) for a 128-row Q tile and writes an unnormalized
// partial O (f32) + per-row (m, l). fa_combine merges <=4 partials per row.
__global__ __launch_bounds__(256, 3) void flash_attn(const u16* __restrict__ Qb,
                                                     const u16* __restrict__ Kb,
                                                     const u16* __restrict__ Vt,
                                                     float* __restrict__ Opart,
                                                     float* __restrict__ ml) {
  __shared__ __attribute__((aligned(16))) u16 KsB[2][4096];
  __shared__ __attribute__((aligned(16))) u16 VsB[2][4096];
  __shared__ __attribute__((aligned(16))) u16 Ps[128 * 72];
  __shared__ __attribute__((aligned(16))) u16 Vone[1024];
  const int e = blockIdx.x, h = blockIdx.y;
  // decode (qb, chunk): group a has 4 qb values with (a+1) chunks each
  const int a = (e < 4) ? 0 : (e < 12) ? 1 : (e < 24) ? 2 : 3;
  const int rr = e - ((a == 0) ? 0 : (a == 1) ? 4 : (a == 2) ? 12 : 24);
  const int qb = 4 * a + rr / (a + 1);
  const int cc = rr % (a + 1);
  const int k0 = cc * 8;
  const int kvTend = 2 * qb + 2;
  const int k1 = (k0 + 8 < kvTend) ? (k0 + 8) : kvTend;
  const int kvh = h >> 2;
  const int pid = (h * 16 + qb) * 4 + cc;

  const int tid = threadIdx.x, wid = tid >> 6, lane = tid & 63;
  const int l16 = lane & 15, quad = lane >> 4;
  const int lrow = lane >> 3, swz = (lane & 7) ^ lrow, sx = l16 & 7;

  // ones-column V-extension tile: B[n][k] swizzled like Vs; n==0 col = 1.0
  for (int i = tid; i < 1024; i += 256) {
    int n = i >> 6, k = i & 63;
    Vone[n * 64 + ((((k >> 3) ^ (n & 7)) << 3) | (k & 7))] = (n == 0) ? 0x3F80 : 0;
  }

  const int q0 = qb * 128 + wid * 32;
  bf16x8 qf[2][2];
#pragma unroll
  for (int mt = 0; mt < 2; ++mt)
#pragma unroll
    for (int ks = 0; ks < 2; ++ks)
      qf[mt][ks] = *(const bf16x8*)(Qb + ((size_t)h * 2048 + q0 + mt * 16 + l16) * 64 +
                                    ks * 32 + quad * 8);

  f32x4 oacc[2][4] = {};
  f32x4 oaccE[2] = {};
  float mrun[2][4];
#pragma unroll
  for (int mt = 0; mt < 2; ++mt)
#pragma unroll
    for (int r = 0; r < 4; ++r) mrun[mt][r] = -3e38f;

  const u16* kgb = Kb + ((size_t)kvh * 2048) * 64;
  const u16* vgb = Vt + (size_t)kvh * 64 * 2048;

#define FA_STAGE(KT, BUF)                                                         \
  {                                                                               \
    const u16* kg_ = kgb + (size_t)(KT)*64 * 64;                                  \
    const u16* vg_ = vgb + (size_t)(KT)*64;                                       \
    _Pragma("unroll") for (int j = 0; j < 2; ++j) {                               \
      int i_ = wid * 2 + j;                                                       \
      gl_lds16(kg_ + (size_t)(i_ * 8 + lrow) * 64 + swz * 8, &KsB[BUF][i_ * 512]);\
      gl_lds16(vg_ + (size_t)(i_ * 8 + lrow) * 2048 + swz * 8, &VsB[BUF][i_ * 512]);\
    }                                                                             \
  }

  FA_STAGE(k0, 0)
  for (int kt = k0; kt < k1; ++kt) {
    const int cur = (kt - k0) & 1;
    __syncthreads();  // drains this tile's staging; protects buffer swap
    if (kt + 1 < k1) FA_STAGE(kt + 1, cur ^ 1)
    const u16* Ks = KsB[cur];
    const u16* Vs = VsB[cur];

    // S = Q K^T  (pre-scaled to exp2 domain)
    f32x4 sacc[2][4] = {};
#pragma unroll
    for (int nt = 0; nt < 4; ++nt) {
      bf16x8 b0 = *(const bf16x8*)(Ks + (nt * 16 + l16) * 64 + ((quad ^ sx) << 3));
      bf16x8 b1 = *(const bf16x8*)(Ks + (nt * 16 + l16) * 64 + (((4 + quad) ^ sx) << 3));
      sacc[0][nt] = __builtin_amdgcn_mfma_f32_16x16x32_bf16(qf[0][0], b0, sacc[0][nt], 0, 0, 0);
      sacc[0][nt] = __builtin_amdgcn_mfma_f32_16x16x32_bf16(qf[0][1], b1, sacc[0][nt], 0, 0, 0);
      sacc[1][nt] = __builtin_amdgcn_mfma_f32_16x16x32_bf16(qf[1][0], b0, sacc[1][nt], 0, 0, 0);
      sacc[1][nt] = __builtin_amdgcn_mfma_f32_16x16x32_bf16(qf[1][1], b1, sacc[1][nt], 0, 0, 0);
    }

    const bool msk = (kt >= 2 * qb);  // only diagonal tiles need causal masking
    f32x4 alv[2];
#pragma unroll
    for (int mt = 0; mt < 2; ++mt) {
#pragma unroll
      for (int r = 0; r < 4; ++r) {
        float sv[4];
        if (msk) {
          const int qg = q0 + mt * 16 + quad * 4 + r;
#pragma unroll
          for (int nt = 0; nt < 4; ++nt) {
            float s = sacc[mt][nt][r];
            if (kt * 64 + nt * 16 + l16 > qg) s = -1e9f;
            sv[nt] = s;
          }
        } else {
#pragma unroll
          for (int nt = 0; nt < 4; ++nt) sv[nt] = sacc[mt][nt][r];
        }
        float mx = fmaxf(fmaxf(sv[0], sv[1]), fmaxf(sv[2], sv[3]));
        mx = fmaxf(mx, __shfl_xor(mx, 1));
        mx = fmaxf(mx, __shfl_xor(mx, 2));
        mx = fmaxf(mx, __shfl_xor(mx, 4));
        mx = fmaxf(mx, __shfl_xor(mx, 8));
        float mn = fmaxf(mrun[mt][r], mx);
        alv[mt][r] = __builtin_amdgcn_exp2f(mrun[mt][r] - mn);
        mrun[mt][r] = mn;
        const int prow = wid * 32 + mt * 16 + quad * 4 + r;
#pragma unroll
        for (int nt = 0; nt < 4; ++nt) {
          float p = __builtin_amdgcn_exp2f(sv[nt] - mn);
          *(__bf16*)&Ps[prow * 72 + nt * 16 + l16] = (__bf16)p;
        }
      }
    }
#pragma unroll
    for (int mt = 0; mt < 2; ++mt) {
#pragma unroll
      for (int nt = 0; nt < 4; ++nt) oacc[mt][nt] *= alv[mt];
      oaccE[mt] *= alv[mt];
    }

    // O += P V ; l-sums via ones tile (same-wave LDS write->read, no barrier)
#pragma unroll
    for (int ks = 0; ks < 2; ++ks) {
      bf16x8 pa0 = *(const bf16x8*)(Ps + (wid * 32 + l16) * 72 + ks * 32 + quad * 8);
      bf16x8 pa1 = *(const bf16x8*)(Ps + (wid * 32 + 16 + l16) * 72 + ks * 32 + quad * 8);
      bf16x8 vo = *(const bf16x8*)(Vone + l16 * 64 + (((ks * 4 + quad) ^ sx) << 3));
#pragma unroll
      for (int nt = 0; nt < 4; ++nt) {
        bf16x8 vb = *(const bf16x8*)(Vs + (nt * 16 + l16) * 64 + (((ks * 4 + quad) ^ sx) << 3));
        oacc[0][nt] = __builtin_amdgcn_mfma_f32_16x16x32_bf16(pa0, vb, oacc[0][nt], 0, 0, 0);
        oacc[1][nt] = __builtin_amdgcn_mfma_f32_16x16x32_bf16(pa1, vb, oacc[1][nt], 0, 0, 0);
      }
      oaccE[0] = __builtin_amdgcn_mfma_f32_16x16x32_bf16(pa0, vo, oaccE[0], 0, 0, 0);
      oaccE[1] = __builtin_amdgcn_mfma_f32_16x16x32_bf16(pa1, vo, oaccE[1], 0, 0, 0);
    }
  }
#undef FA_STAGE

  // epilogue: write unnormalized partial O + per-row (m, l)
  float* Op = Opart + (size_t)pid * 128 * 64;
#pragma unroll
  for (int mt = 0; mt < 2; ++mt) {
    float lb[4];
#pragma unroll
    for (int r = 0; r < 4; ++r) lb[r] = __shfl(oaccE[mt][r], lane & 48);
#pragma unroll
    for (int nt = 0; nt < 4; ++nt)
#pragma unroll
      for (int r = 0; r < 4; ++r) {
        int row = wid * 32 + mt * 16 + quad * 4 + r;
        Op[(size_t)row * 64 + nt * 16 + l16] = oacc[mt][nt][r];
      }
    if (l16 == 0) {
#pragma unroll
      for (int r = 0; r < 4; ++r) {
        int row = wid * 32 + mt * 16 + quad * 4 + r;
        ml[((size_t)pid * 128 + row) * 2] = mrun[mt][r];
        ml[((size_t)pid * 128 + row) * 2 + 1] = lb[r];
      }
    }
  }
}

// ---------------- combine partials: O = sum(w_c O_c) / sum(w_c l_c) ----------------
__global__ __launch_bounds__(256) void fa_combine(const float* __restrict__ Opart,
                                                  const float* __restrict__ ml,
                                                  u16* __restrict__ Ob) {
  const int qb = blockIdx.x, h = blockIdx.y;
  const int C = (qb >> 2) + 1;
  const int t = threadIdx.x;
  const int base = (h * 16 + qb) * 4;
#pragma unroll
  for (int u = 0; u < 8; ++u) {
    int unit = u * 256 + t;
    int row = unit >> 4, d4 = unit & 15;
    float mstar = -3e38f;
    for (int c = 0; c < C; ++c)
      mstar = fmaxf(mstar, ml[((size_t)(base + c) * 128 + row) * 2]);
    float4 o = {0.f, 0.f, 0.f, 0.f};
    float lsum = 0.f;
    for (int c = 0; c < C; ++c) {
      const float* mlp = &ml[((size_t)(base + c) * 128 + row) * 2];
      float w = __builtin_amdgcn_exp2f(mlp[0] - mstar);
      float4 v = ((const float4*)(Opart + ((size_t)(base + c) * 128 + row) * 64))[d4];
      o.x += w * v.x; o.y += w * v.y; o.z += w * v.z; o.w += w * v.w;
      lsum += w * mlp[1];
    }
    float inv = 1.0f / lsum;
    uint2 pk;
    pk.x = (u32)f2bf(o.x * inv) | ((u32)f2bf(o.y * inv) << 16);
    pk.y = (u32)f2bf(o.z * inv) | ((u32)f2bf(o.w * inv) << 16);
    *(uint2*)(Ob + (size_t)(qb * 128 + row) * 2048 + h * 64 + d4 * 4) = pk;
  }
}

// ---------------- launcher ----------------
extern "C" void kernel_launch(void* const* d_in, const int* in_sizes, int n_in,
                              void* d_out, int out_size, void* d_ws, size_t ws_size,
                              hipStream_t stream) {
  (void)in_sizes; (void)n_in; (void)out_size;
  const float* hidden = (const float*)d_in[0];
  const float* cosb   = (const float*)d_in[1];
  const float* sinb   = (const float*)d_in[2];
  const int*   pos    = (const int*)d_in[3];
  const float* Wq     = (const float*)d_in[4];
  const float* Wk     = (const float*)d_in[5];
  const float* Wv     = (const float*)d_in[6];
  const float* Wo     = (const float*)d_in[7];
  const float* tWq    = (const float*)d_in[8];
  const float* tWv    = (const float*)d_in[9];
  const float* alpha  = (const float*)d_in[10];
  float* out = (float*)d_out;

  const bool big = ws_size >= (size_t)120 * 1024 * 1024;
  const int Pq = big ? 2 : 1;
  const int Pt = big ? 16 : 1;
  const int Po = big ? 3 : 1;

  char* ws = (char*)d_ws;
  size_t off = 0;
  auto alloc = [&](size_t bytes) -> void* {
    void* p = ws + off;
    off += (bytes + 255) & ~(size_t)255;
    return p;
  };
  u16*   WoT   = (u16*)alloc(2048ull * 2048 * 2);
  u16*   Tt    = (u16*)alloc(64ull * 3072 * 2);
  u16*   Qb    = (u16*)alloc(32ull * 2048 * 64 * 2);
  u16*   Kb    = (u16*)alloc(8ull * 2048 * 64 * 2);
  u16*   Vt    = (u16*)alloc(8ull * 64 * 2048 * 2);
  u16*   Ob    = (u16*)alloc(2048ull * 2048 * 2);
  u16*   featb = (u16*)alloc(2048ull * 3072 * 2);
  float* tokq  = (float*)alloc(2048ull * 32 * 4);
  float* tokv  = (float*)alloc(2048ull * 32 * 4);
  u16*   Vb    = big ? (u16*)alloc(8ull * 2048 * 64 * 2) : nullptr;
  // early region (dead after prep) -> reused for flash partials -> out partials
  size_t E = off;
  u16*   Xb      = (u16*)alloc(2048ull * 2048 * 2);
  u16*   WqkvT   = (u16*)alloc(3072ull * 2048 * 2);
  float* qkvPart = (float*)alloc((size_t)Pq * 2048 * 3072 * 4);
  float* qkv     = qkvPart;
  float* tokPart = (float*)(ws + E);
  float* Opart   = (float*)(ws + E);                       // 2048*128*64*4 = 64 MB
  float* mlbuf   = (float*)(ws + E + 2048ull * 128 * 64 * 4);  // +2 MB
  float* outPart = (float*)(ws + E);

  cvt_bf16<<<2048, 256, 0, stream>>>(hidden, Xb, 2048 * 2048 / 8);
  transpose_cvt<<<dim3(32, 32), 256, 0, stream>>>(Wq, WqkvT, 2048, 2048);
  transpose_cvt<<<dim3(8, 32), 256, 0, stream>>>(Wk, WqkvT + 2048ull * 2048, 2048, 512);
  transpose_cvt<<<dim3(8, 32), 256, 0, stream>>>(Wv, WqkvT + 2560ull * 2048, 2048, 512);
  transpose_cvt<<<dim3(32, 32), 256, 0, stream>>>(Wo, WoT, 2048, 2048);
  transpose_cvt<<<dim3(1, 48), 256, 0, stream>>>(tWq, Tt, 3072, 32);
  transpose_cvt<<<dim3(1, 48), 256, 0, stream>>>(tWv, Tt + 32ull * 3072, 3072, 32);

  gemm_bt<2, 2><<<dim3(24, 16, Pq), 256, 0, stream>>>(
      Xb, WqkvT, qkvPart, 2048, 3072, 2048, (32 + Pq - 1) / Pq);
  reduce_gelu<<<6144, 256, 0, stream>>>(qkvPart, Pq, 2048 * 3072 / 4, featb);

  gemm_bt<4, 1><<<dim3(1, 8, Pt), 256, 0, stream>>>(
      featb, Tt, tokPart, 2048, 64, 3072, (48 + Pt - 1) / Pt);
  reduce_tanh<<<512, 256, 0, stream>>>(tokPart, Pt, 2048 * 64, tokq, tokv);

  prep_qkv<<<2048, 256, 0, stream>>>(qkv, tokq, tokv, alpha, cosb, sinb, pos,
                                     Qb, Kb, Vt, Vb);
  if (big) vtrans<<<dim3(32, 8), 256, 0, stream>>>(Vb, Vt);

  flash_attn<<<dim3(40, 32), 256, 0, stream>>>(Qb, Kb, Vt, Opart, mlbuf);
  fa_combine<<<dim3(16, 32), 256, 0, stream>>>(Opart, mlbuf, Ob);

  gemm_bt<2, 2><<<dim3(16, 16, Po), 256, 0, stream>>>(
      Ob, WoT, outPart, 2048, 2048, 2048, (32 + Po - 1) / Po);
  reduce_add<<<4096, 256, 0, stream>>>(outPart, Po, 2048 * 2048 / 4, out);
}

// Round 5
// 346.400 us; speedup vs baseline: 1.0573x; 1.0573x over previous
//
#include <hip/hip_runtime.h>
#include <cmath>

typedef __bf16 bf16x8 __attribute__((ext_vector_type(8)));
typedef __bf16 bf16x4 __attribute__((ext_vector_type(4)));
typedef float f32x4 __attribute__((ext_vector_type(4)));
typedef unsigned short u16;
typedef unsigned int u32;

__device__ __forceinline__ u16 f2bf(float f) {
  union { float f; unsigned int u; } v; v.f = f;
  unsigned int u = v.u;
  return (u16)((u + 0x7FFFu + ((u >> 16) & 1u)) >> 16);
}

__device__ __forceinline__ float geluf(float x) {
  return 0.5f * x * (1.0f + erff(x * 0.7071067811865475f));
}

// async global->LDS, 16B per lane. LDS dest = wave-uniform base + lane*16.
__device__ __forceinline__ void gl_lds16(const void* g, void* l) {
  __builtin_amdgcn_global_load_lds(
      (const __attribute__((address_space(1))) u32*)g,
      (__attribute__((address_space(3))) u32*)l, 16, 0, 0);
}

// ---------------- elementwise f32 -> bf16 (8 elems/thread) ----------------
__global__ __launch_bounds__(256) void cvt_bf16(const float* __restrict__ in,
                                                u16* __restrict__ out, int n8) {
  int i = blockIdx.x * 256 + threadIdx.x;
  if (i >= n8) return;
  const float4* p = (const float4*)in + 2 * (size_t)i;
  float4 a = p[0], b = p[1];
  uint4 o;
  o.x = (unsigned)f2bf(a.x) | ((unsigned)f2bf(a.y) << 16);
  o.y = (unsigned)f2bf(a.z) | ((unsigned)f2bf(a.w) << 16);
  o.z = (unsigned)f2bf(b.x) | ((unsigned)f2bf(b.y) << 16);
  o.w = (unsigned)f2bf(b.z) | ((unsigned)f2bf(b.w) << 16);
  ((uint4*)out)[i] = o;
}

// ---------- LDS-tiled transpose + cvt: in (R x C) f32 -> out (C x R) bf16 ----------
__global__ __launch_bounds__(256) void transpose_cvt(const float* __restrict__ in,
                                                     u16* __restrict__ out,
                                                     int R, int C) {
  __shared__ float tile[64][65];
  const int t = threadIdx.x;
  const int c0 = blockIdx.x * 64, r0 = blockIdx.y * 64;
  const int lr = t >> 6, lc = t & 63;
#pragma unroll
  for (int p = 0; p < 16; ++p) {
    int r = p * 4 + lr;
    float v = 0.f;
    if (r0 + r < R && c0 + lc < C) v = in[(size_t)(r0 + r) * C + c0 + lc];
    tile[r][lc] = v;
  }
  __syncthreads();
#pragma unroll
  for (int p = 0; p < 16; ++p) {
    int c = p * 4 + lr;
    if (c0 + c < C && r0 + lc < R)
      out[(size_t)(c0 + c) * R + r0 + lc] = f2bf(tile[lc][c]);
  }
}

// ---------------- bf16 MFMA GEMM: Cpart[z] = A(MxK) * Bt(NxK)^T over K-chunk z --------
template <int WR, int WC>
__global__ __launch_bounds__(256, 3) void gemm_bt(const u16* __restrict__ A,
                                                  const u16* __restrict__ Bt,
                                                  float* __restrict__ Cpart,
                                                  int M, int N, int K, int kPer) {
  constexpr int BM = WR * 64, BN = WC * 64;
  __shared__ __attribute__((aligned(16))) u16 As[BM * 64];
  __shared__ __attribute__((aligned(16))) u16 Bs[BN * 64];
  const int tid = threadIdx.x, wid = tid >> 6, lane = tid & 63;
  const int l16 = lane & 15, quad = lane >> 4;
  const int wm = (wid % WR) * 64, wn = (wid / WR) * 64;
  const int m0 = blockIdx.y * BM, n0 = blockIdx.x * BN;
  const int kIters = K >> 6;
  const int kStart = blockIdx.z * kPer;
  const int kEnd = (kStart + kPer < kIters) ? (kStart + kPer) : kIters;

  const int lrow = lane >> 3;
  const int swz = (lane & 7) ^ lrow;
  const u16* gAb = A + (size_t)m0 * K + (size_t)swz * 8;
  const u16* gBb = Bt + (size_t)n0 * K + (size_t)swz * 8;
  const int sx = l16 & 7;

  f32x4 acc[4][4] = {};
  for (int kt = kStart; kt < kEnd; ++kt) {
    __syncthreads();
    const u16* gA = gAb + (size_t)kt * 64;
    const u16* gB = gBb + (size_t)kt * 64;
#pragma unroll
    for (int j = 0; j < BM / 32; ++j) {
      int i = wid * (BM / 32) + j;
      gl_lds16(gA + (size_t)(i * 8 + lrow) * K, &As[i * 512]);
    }
#pragma unroll
    for (int j = 0; j < BN / 32; ++j) {
      int i = wid * (BN / 32) + j;
      gl_lds16(gB + (size_t)(i * 8 + lrow) * K, &Bs[i * 512]);
    }
    __syncthreads();
    bf16x8 af[4][2], bfr[4][2];
#pragma unroll
    for (int mt = 0; mt < 4; ++mt)
#pragma unroll
      for (int ks = 0; ks < 2; ++ks)
        af[mt][ks] = *(const bf16x8*)(&As[(wm + mt * 16 + l16) * 64 +
                                          (((ks * 4 + quad) ^ sx) * 8)]);
#pragma unroll
    for (int nt = 0; nt < 4; ++nt)
#pragma unroll
      for (int ks = 0; ks < 2; ++ks)
        bfr[nt][ks] = *(const bf16x8*)(&Bs[(wn + nt * 16 + l16) * 64 +
                                           (((ks * 4 + quad) ^ sx) * 8)]);
#pragma unroll
    for (int mt = 0; mt < 4; ++mt)
#pragma unroll
      for (int nt = 0; nt < 4; ++nt)
#pragma unroll
        for (int ks = 0; ks < 2; ++ks)
          acc[mt][nt] = __builtin_amdgcn_mfma_f32_16x16x32_bf16(
              af[mt][ks], bfr[nt][ks], acc[mt][nt], 0, 0, 0);
  }

  float* C = Cpart + (size_t)blockIdx.z * M * N;
#pragma unroll
  for (int mt = 0; mt < 4; ++mt)
#pragma unroll
    for (int nt = 0; nt < 4; ++nt)
#pragma unroll
      for (int r = 0; r < 4; ++r) {
        int row = m0 + wm + mt * 16 + quad * 4 + r;
        int col = n0 + wn + nt * 16 + l16;
        C[(size_t)row * N + col] = acc[mt][nt][r];
      }
}

// ---------------- reduce kernels (split-K epilogues) ----------------
__global__ __launch_bounds__(256) void reduce_gelu(float* __restrict__ base, int P,
                                                   int n4, u16* __restrict__ gout) {
  int i = blockIdx.x * 256 + threadIdx.x;
  if (i >= n4) return;
  size_t n = (size_t)n4 * 4;
  float4 v = ((const float4*)base)[i];
  for (int p = 1; p < P; ++p) {
    float4 w = ((const float4*)(base + (size_t)p * n))[i];
    v.x += w.x; v.y += w.y; v.z += w.z; v.w += w.w;
  }
  if (P > 1) ((float4*)base)[i] = v;
  uint2 o;
  o.x = (u32)f2bf(geluf(v.x)) | ((u32)f2bf(geluf(v.y)) << 16);
  o.y = (u32)f2bf(geluf(v.z)) | ((u32)f2bf(geluf(v.w)) << 16);
  ((uint2*)gout)[i] = o;
}

__global__ __launch_bounds__(256) void reduce_add(const float* __restrict__ base, int P,
                                                  int n4, float* __restrict__ dst) {
  int i = blockIdx.x * 256 + threadIdx.x;
  if (i >= n4) return;
  size_t n = (size_t)n4 * 4;
  float4 v = ((const float4*)base)[i];
  for (int p = 1; p < P; ++p) {
    float4 w = ((const float4*)(base + (size_t)p * n))[i];
    v.x += w.x; v.y += w.y; v.z += w.z; v.w += w.w;
  }
  ((float4*)dst)[i] = v;
}

__global__ __launch_bounds__(256) void reduce_tanh(const float* __restrict__ base, int P,
                                                   int n, float* __restrict__ tokq,
                                                   float* __restrict__ tokv) {
  int i = blockIdx.x * 256 + threadIdx.x;
  if (i >= n) return;
  float v = base[i];
  for (int p = 1; p < P; ++p) v += base[(size_t)p * n + i];
  float t = tanhf(v);
  int col = i & 63, row = i >> 6;
  if (col < 32) tokq[row * 32 + col] = t;
  else          tokv[row * 32 + (col - 32)] = t;
}

// ---------------- prep: tau scaling + RoPE + layouts for attention ----------------
// Q is pre-scaled by 0.125*log2(e) so flash softmax runs in exp2 domain.
#define QSCALE 0.18033688011112042f
__global__ __launch_bounds__(256) void prep_qkv(const float* __restrict__ qkv,
                                                const float* __restrict__ tokq,
                                                const float* __restrict__ tokv,
                                                const float* __restrict__ alpha,
                                                const float* __restrict__ cosb,
                                                const float* __restrict__ sinb,
                                                const int* __restrict__ pos_ids,
                                                u16* __restrict__ Qb,
                                                u16* __restrict__ Kb,
                                                u16* __restrict__ Vt,
                                                u16* __restrict__ Vb) {
  const int s = blockIdx.x;
  const int tid = threadIdx.x;
  __shared__ float cs[16], sn[16], tq_s[32], tv_s[32];
  if (tid < 16) { cs[tid] = cosb[s * 16 + tid]; sn[tid] = sinb[s * 16 + tid]; }
  if (tid < 32) {
    float p = (float)pos_ids[s] + 1.0f;
    float sig = 1.0f / (1.0f + __expf(-alpha[tid] * logf(p)));
    float taupos = 0.5f + sig;
    tq_s[tid] = (tokq[s * 32 + tid] + taupos) * QSCALE;
    tv_s[tid] = tokv[s * 32 + tid] + taupos;
  }
  __syncthreads();
  const float* row = qkv + (size_t)s * 3072;

  for (int idx = tid; idx < 2048; idx += 256) {
    int h = idx >> 6, d = idx & 63;
    float tq = tq_s[h];
    float v;
    if (d < 32) {
      int i = d >> 1;
      float xr = row[h * 64 + i] * tq, xi = row[h * 64 + 16 + i] * tq;
      v = (d & 1) ? (xr * sn[i] + xi * cs[i]) : (xr * cs[i] - xi * sn[i]);
    } else v = row[h * 64 + d] * tq;
    Qb[((size_t)h * 2048 + s) * 64 + d] = f2bf(v);
  }
  for (int idx = tid; idx < 512; idx += 256) {
    int h = idx >> 6, d = idx & 63;
    const float* kr = row + 2048;
    float v;
    if (d < 32) {
      int i = d >> 1;
      float xr = kr[h * 64 + i], xi = kr[h * 64 + 16 + i];
      v = (d & 1) ? (xr * sn[i] + xi * cs[i]) : (xr * cs[i] - xi * sn[i]);
    } else v = kr[h * 64 + d];
    Kb[((size_t)h * 2048 + s) * 64 + d] = f2bf(v);
  }
  for (int idx = tid; idx < 512; idx += 256) {
    int h = idx >> 6, d = idx & 63;
    float v = row[2560 + h * 64 + d] * tv_s[h];
    u16 b = f2bf(v);
    if (Vb) Vb[((size_t)h * 2048 + s) * 64 + d] = b;
    else    Vt[((size_t)h * 64 + d) * 2048 + s] = b;
  }
}

// ---------------- bf16 transpose Vb[h][s][d] -> Vt[h][d][s] ----------------
__global__ __launch_bounds__(256) void vtrans(const u16* __restrict__ Vb,
                                              u16* __restrict__ Vt) {
  __shared__ u16 t[64][68];
  const int s0 = blockIdx.x * 64, h = blockIdx.y;
  const int tid = threadIdx.x;
  const u16* src = Vb + ((size_t)h * 2048 + s0) * 64;
#pragma unroll
  for (int p = 0; p < 4; ++p) {
    int v = p * 256 + tid;
    int r = v >> 4, c = (v & 15) * 4;
    uint2 w = *(const uint2*)(src + (size_t)r * 64 + c);
    t[r][c] = (u16)(w.x & 0xffff); t[r][c + 1] = (u16)(w.x >> 16);
    t[r][c + 2] = (u16)(w.y & 0xffff); t[r][c + 3] = (u16)(w.y >> 16);
  }
  __syncthreads();
  u16* dst = Vt + (size_t)h * 64 * 2048 + s0;
#pragma unroll
  for (int p = 0; p < 4; ++p) {
    int v = p * 256 + tid;
    int d = v >> 4, s = (v & 15) * 4;
    uint2 w;
    w.x = (u32)t[s][d] | ((u32)t[s + 1][d] << 16);
    w.y = (u32)t[s + 2][d] | ((u32)t[s + 3][d] << 16);
    *(uint2*)(dst + (size_t)d * 2048 + s) = w;
  }
}

// ---------------- flash attention v4: KV-split + TRANSPOSED softmax ----------------
// S^T = K Q^T puts q in lanes (col=lane&15) and k in regs -> row-softmax is mostly
// in-register (2 shuffles/q-half, scalar m/l, b64 P-writes). PV: O^T = V^T P.
// Chunks of 6 K-tiles; 51 (qb,cc) pairs x 32 heads = 1632 blocks, heaviest first.
__global__ __launch_bounds__(256, 3) void flash_attn(const u16* __restrict__ Qb,
                                                     const u16* __restrict__ Kb,
                                                     const u16* __restrict__ Vt,
                                                     float* __restrict__ Opart,
                                                     float* __restrict__ ml) {
  __shared__ __attribute__((aligned(16))) u16 KsB[2][4096];
  __shared__ __attribute__((aligned(16))) u16 VsB[2][4096];
  __shared__ __attribute__((aligned(16))) u16 Ps[128 * 80];
  const int e = 50 - blockIdx.x;  // reversed: heaviest (qb=15) first
  const int h = blockIdx.y, kvh = h >> 2;
  // decode e -> (qb, cc): group a (a=0..5) holds qb=3a..3a+2, each with a+1 chunks
  int a = 0;
  while (3 * (a + 1) * (a + 2) / 2 <= e) ++a;
  const int rem = e - 3 * a * (a + 1) / 2;
  const int qb = 3 * a + rem / (a + 1);
  const int cc = rem % (a + 1);
  const int k0 = cc * 6;
  const int kvTend = 2 * qb + 2;
  const int k1 = (k0 + 6 < kvTend) ? (k0 + 6) : kvTend;
  const int pid = h * 51 + e;  // e is already the (qb,cc) linear index

  const int tid = threadIdx.x, wid = tid >> 6, lane = tid & 63;
  const int l16 = lane & 15, quad = lane >> 4;
  const int lrow = lane >> 3, swz = (lane & 7) ^ lrow, sx = l16 & 7;

  const int q0 = qb * 128 + wid * 32;
  bf16x8 qf[2][2];
#pragma unroll
  for (int mt = 0; mt < 2; ++mt)
#pragma unroll
    for (int ks = 0; ks < 2; ++ks)
      qf[mt][ks] = *(const bf16x8*)(Qb + ((size_t)h * 2048 + q0 + mt * 16 + l16) * 64 +
                                    ks * 32 + quad * 8);

  f32x4 oacc[2][4] = {};          // O^T frags: [q-half][d-frag], lane q = l16
  float mrun[2] = {-3e38f, -3e38f};
  float lrun[2] = {0.f, 0.f};

  const u16* kgb = Kb + ((size_t)kvh * 2048) * 64;
  const u16* vgb = Vt + (size_t)kvh * 64 * 2048;

#define FA_STAGE(KT, BUF)                                                         \
  {                                                                               \
    const u16* kg_ = kgb + (size_t)(KT)*64 * 64;                                  \
    const u16* vg_ = vgb + (size_t)(KT)*64;                                       \
    _Pragma("unroll") for (int j = 0; j < 2; ++j) {                               \
      int i_ = wid * 2 + j;                                                       \
      gl_lds16(kg_ + (size_t)(i_ * 8 + lrow) * 64 + swz * 8, &KsB[BUF][i_ * 512]);\
      gl_lds16(vg_ + (size_t)(i_ * 8 + lrow) * 2048 + swz * 8, &VsB[BUF][i_ * 512]);\
    }                                                                             \
  }

  FA_STAGE(k0, 0)
  for (int kt = k0; kt < k1; ++kt) {
    const int cur = (kt - k0) & 1;
    __syncthreads();
    if (kt + 1 < k1) FA_STAGE(kt + 1, cur ^ 1)
    const u16* Ks = KsB[cur];
    const u16* Vs = VsB[cur];

    // S^T = K Q^T : sacc[mt][kf], C row = k (quad*4+r+16kf), col = q (l16)
    f32x4 sacc[2][4] = {};
#pragma unroll
    for (int kf = 0; kf < 4; ++kf) {
      bf16x8 a0 = *(const bf16x8*)(Ks + (kf * 16 + l16) * 64 + ((quad ^ sx) << 3));
      bf16x8 a1 = *(const bf16x8*)(Ks + (kf * 16 + l16) * 64 + (((4 + quad) ^ sx) << 3));
      sacc[0][kf] = __builtin_amdgcn_mfma_f32_16x16x32_bf16(a0, qf[0][0], sacc[0][kf], 0, 0, 0);
      sacc[0][kf] = __builtin_amdgcn_mfma_f32_16x16x32_bf16(a1, qf[0][1], sacc[0][kf], 0, 0, 0);
      sacc[1][kf] = __builtin_amdgcn_mfma_f32_16x16x32_bf16(a0, qf[1][0], sacc[1][kf], 0, 0, 0);
      sacc[1][kf] = __builtin_amdgcn_mfma_f32_16x16x32_bf16(a1, qf[1][1], sacc[1][kf], 0, 0, 0);
    }

    const bool msk = (kt >= 2 * qb);  // diagonal tiles only
#pragma unroll
    for (int mt = 0; mt < 2; ++mt) {
      const int qg = q0 + mt * 16 + l16;       // this lane's q (fixed)
      if (msk) {
        const int kb = kt * 64 + quad * 4;
#pragma unroll
        for (int kf = 0; kf < 4; ++kf)
#pragma unroll
          for (int r = 0; r < 4; ++r)
            if (kb + kf * 16 + r > qg) sacc[mt][kf][r] = -1e9f;
      }
      // in-register max over 16 k-values, then 2 cross-quad shuffles
      f32x4 m4 = sacc[mt][0];
      m4 = __builtin_elementwise_max(m4, sacc[mt][1]);
      m4 = __builtin_elementwise_max(m4, sacc[mt][2]);
      m4 = __builtin_elementwise_max(m4, sacc[mt][3]);
      float mx = fmaxf(fmaxf(m4[0], m4[1]), fmaxf(m4[2], m4[3]));
      mx = fmaxf(mx, __shfl_xor(mx, 16));
      mx = fmaxf(mx, __shfl_xor(mx, 32));
      float mn = fmaxf(mrun[mt], mx);
      float al = __builtin_amdgcn_exp2f(mrun[mt] - mn);
      mrun[mt] = mn;
      // exp2 + pack to Ps[q][k] (A-layout for PV), in-register partial sum
      float ps = 0.f;
      const int prow = wid * 32 + mt * 16 + l16;
#pragma unroll
      for (int kf = 0; kf < 4; ++kf) {
        bf16x4 pk;
#pragma unroll
        for (int r = 0; r < 4; ++r) {
          float p = __builtin_amdgcn_exp2f(sacc[mt][kf][r] - mn);
          ps += p;
          pk[r] = (__bf16)p;
        }
        *(bf16x4*)(Ps + prow * 80 + kf * 16 + quad * 4) = pk;
      }
      ps += __shfl_xor(ps, 16);
      ps += __shfl_xor(ps, 32);
      lrun[mt] = lrun[mt] * al + ps;
#pragma unroll
      for (int df = 0; df < 4; ++df) oacc[mt][df] *= al;
    }

    // O^T += V^T P : A = Vs[d][k], B = Ps[q][k] (same-wave LDS write->read)
#pragma unroll
    for (int ks = 0; ks < 2; ++ks) {
      bf16x8 b0 = *(const bf16x8*)(Ps + (wid * 32 + l16) * 80 + ks * 32 + quad * 8);
      bf16x8 b1 = *(const bf16x8*)(Ps + (wid * 32 + 16 + l16) * 80 + ks * 32 + quad * 8);
#pragma unroll
      for (int df = 0; df < 4; ++df) {
        bf16x8 va = *(const bf16x8*)(Vs + (df * 16 + l16) * 64 + (((ks * 4 + quad) ^ sx) << 3));
        oacc[0][df] = __builtin_amdgcn_mfma_f32_16x16x32_bf16(va, b0, oacc[0][df], 0, 0, 0);
        oacc[1][df] = __builtin_amdgcn_mfma_f32_16x16x32_bf16(va, b1, oacc[1][df], 0, 0, 0);
      }
    }
  }
#undef FA_STAGE

  // epilogue: unnormalized partial O (row q, col d; float4 per d-frag) + (m, l)
  float* Op = Opart + (size_t)pid * 128 * 64;
#pragma unroll
  for (int mt = 0; mt < 2; ++mt) {
    const int qrow = wid * 32 + mt * 16 + l16;
#pragma unroll
    for (int df = 0; df < 4; ++df)
      *(f32x4*)(Op + (size_t)qrow * 64 + df * 16 + quad * 4) = oacc[mt][df];
    if (quad == 0) {
      ml[((size_t)pid * 128 + qrow) * 2] = mrun[mt];
      ml[((size_t)pid * 128 + qrow) * 2 + 1] = lrun[mt];
    }
  }
}

// ---------------- combine partials: O = sum(w_c O_c) / sum(w_c l_c) ----------------
__global__ __launch_bounds__(256) void fa_combine(const float* __restrict__ Opart,
                                                  const float* __restrict__ ml,
                                                  u16* __restrict__ Ob) {
  const int qb = blockIdx.x, h = blockIdx.y;
  const int C = (2 * qb + 7) / 6;                  // chunks for this qb
  const int aa = qb / 3, bb = qb % 3;
  const int base = h * 51 + 3 * aa * (aa + 1) / 2 + bb * (aa + 1);
  const int t = threadIdx.x;
#pragma unroll
  for (int u = 0; u < 8; ++u) {
    int unit = u * 256 + t;
    int row = unit >> 4, d4 = unit & 15;
    float mstar = -3e38f;
    for (int c = 0; c < C; ++c)
      mstar = fmaxf(mstar, ml[((size_t)(base + c) * 128 + row) * 2]);
    float4 o = {0.f, 0.f, 0.f, 0.f};
    float lsum = 0.f;
    for (int c = 0; c < C; ++c) {
      const float* mlp = &ml[((size_t)(base + c) * 128 + row) * 2];
      float w = __builtin_amdgcn_exp2f(mlp[0] - mstar);
      float4 v = ((const float4*)(Opart + ((size_t)(base + c) * 128 + row) * 64))[d4];
      o.x += w * v.x; o.y += w * v.y; o.z += w * v.z; o.w += w * v.w;
      lsum += w * mlp[1];
    }
    float inv = 1.0f / lsum;
    uint2 pk;
    pk.x = (u32)f2bf(o.x * inv) | ((u32)f2bf(o.y * inv) << 16);
    pk.y = (u32)f2bf(o.z * inv) | ((u32)f2bf(o.w * inv) << 16);
    *(uint2*)(Ob + (size_t)(qb * 128 + row) * 2048 + h * 64 + d4 * 4) = pk;
  }
}

// ---------------- launcher ----------------
extern "C" void kernel_launch(void* const* d_in, const int* in_sizes, int n_in,
                              void* d_out, int out_size, void* d_ws, size_t ws_size,
                              hipStream_t stream) {
  (void)in_sizes; (void)n_in; (void)out_size;
  const float* hidden = (const float*)d_in[0];
  const float* cosb   = (const float*)d_in[1];
  const float* sinb   = (const float*)d_in[2];
  const int*   pos    = (const int*)d_in[3];
  const float* Wq     = (const float*)d_in[4];
  const float* Wk     = (const float*)d_in[5];
  const float* Wv     = (const float*)d_in[6];
  const float* Wo     = (const float*)d_in[7];
  const float* tWq    = (const float*)d_in[8];
  const float* tWv    = (const float*)d_in[9];
  const float* alpha  = (const float*)d_in[10];
  float* out = (float*)d_out;

  const bool big = ws_size >= (size_t)120 * 1024 * 1024;
  const int Pq = big ? 2 : 1;
  const int Pt = big ? 16 : 1;
  const int Po = big ? 3 : 1;

  char* ws = (char*)d_ws;
  size_t off = 0;
  auto alloc = [&](size_t bytes) -> void* {
    void* p = ws + off;
    off += (bytes + 255) & ~(size_t)255;
    return p;
  };
  u16*   WoT   = (u16*)alloc(2048ull * 2048 * 2);
  u16*   Tt    = (u16*)alloc(64ull * 3072 * 2);
  u16*   Qb    = (u16*)alloc(32ull * 2048 * 64 * 2);
  u16*   Kb    = (u16*)alloc(8ull * 2048 * 64 * 2);
  u16*   Vt    = (u16*)alloc(8ull * 64 * 2048 * 2);
  u16*   Ob    = (u16*)alloc(2048ull * 2048 * 2);
  u16*   featb = (u16*)alloc(2048ull * 3072 * 2);
  float* tokq  = (float*)alloc(2048ull * 32 * 4);
  float* tokv  = (float*)alloc(2048ull * 32 * 4);
  u16*   Vb    = big ? (u16*)alloc(8ull * 2048 * 64 * 2) : nullptr;
  // early region (dead after prep) -> reused for flash partials -> out partials
  size_t E = off;
  u16*   Xb      = (u16*)alloc(2048ull * 2048 * 2);
  u16*   WqkvT   = (u16*)alloc(3072ull * 2048 * 2);
  float* qkvPart = (float*)alloc((size_t)Pq * 2048 * 3072 * 4);
  float* qkv     = qkvPart;
  float* tokPart = (float*)(ws + E);
  float* Opart   = (float*)(ws + E);                           // 1632*128*64*4 = 53.5 MB
  float* mlbuf   = (float*)(ws + E + 1632ull * 128 * 64 * 4);  // +1.7 MB
  float* outPart = (float*)(ws + E);

  cvt_bf16<<<2048, 256, 0, stream>>>(hidden, Xb, 2048 * 2048 / 8);
  transpose_cvt<<<dim3(32, 32), 256, 0, stream>>>(Wq, WqkvT, 2048, 2048);
  transpose_cvt<<<dim3(8, 32), 256, 0, stream>>>(Wk, WqkvT + 2048ull * 2048, 2048, 512);
  transpose_cvt<<<dim3(8, 32), 256, 0, stream>>>(Wv, WqkvT + 2560ull * 2048, 2048, 512);
  transpose_cvt<<<dim3(32, 32), 256, 0, stream>>>(Wo, WoT, 2048, 2048);
  transpose_cvt<<<dim3(1, 48), 256, 0, stream>>>(tWq, Tt, 3072, 32);
  transpose_cvt<<<dim3(1, 48), 256, 0, stream>>>(tWv, Tt + 32ull * 3072, 3072, 32);

  gemm_bt<2, 2><<<dim3(24, 16, Pq), 256, 0, stream>>>(
      Xb, WqkvT, qkvPart, 2048, 3072, 2048, (32 + Pq - 1) / Pq);
  reduce_gelu<<<6144, 256, 0, stream>>>(qkvPart, Pq, 2048 * 3072 / 4, featb);

  gemm_bt<4, 1><<<dim3(1, 8, Pt), 256, 0, stream>>>(
      featb, Tt, tokPart, 2048, 64, 3072, (48 + Pt - 1) / Pt);
  reduce_tanh<<<512, 256, 0, stream>>>(tokPart, Pt, 2048 * 64, tokq, tokv);

  prep_qkv<<<2048, 256, 0, stream>>>(qkv, tokq, tokv, alpha, cosb, sinb, pos,
                                     Qb, Kb, Vt, Vb);
  if (big) vtrans<<<dim3(32, 8), 256, 0, stream>>>(Vb, Vt);

  flash_attn<<<dim3(51, 32), 256, 0, stream>>>(Qb, Kb, Vt, Opart, mlbuf);
  fa_combine<<<dim3(16, 32), 256, 0, stream>>>(Opart, mlbuf, Ob);

  gemm_bt<2, 2><<<dim3(16, 16, Po), 256, 0, stream>>>(
      Ob, WoT, outPart, 2048, 2048, 2048, (32 + Po - 1) / Po);
  reduce_add<<<4096, 256, 0, stream>>>(outPart, Po, 2048 * 2048 / 4, out);
}

// Round 6
// 288.501 us; speedup vs baseline: 1.2695x; 1.2007x over previous
//
#include <hip/hip_runtime.h>
#include <cmath>

typedef __bf16 bf16x8 __attribute__((ext_vector_type(8)));
typedef __bf16 bf16x4 __attribute__((ext_vector_type(4)));
typedef float f32x4 __attribute__((ext_vector_type(4)));
typedef unsigned short u16;
typedef unsigned int u32;

__device__ __forceinline__ u16 f2bf(float f) {
  union { float f; unsigned int u; } v; v.f = f;
  unsigned int u = v.u;
  return (u16)((u + 0x7FFFu + ((u >> 16) & 1u)) >> 16);
}

__device__ __forceinline__ float geluf(float x) {
  return 0.5f * x * (1.0f + erff(x * 0.7071067811865475f));
}

// async global->LDS, 16B per lane. LDS dest = wave-uniform base + lane*16.
__device__ __forceinline__ void gl_lds16(const void* g, void* l) {
  __builtin_amdgcn_global_load_lds(
      (const __attribute__((address_space(1))) u32*)g,
      (__attribute__((address_space(3))) u32*)l, 16, 0, 0);
}

// ---------------- elementwise f32 -> bf16 (8 elems/thread) ----------------
__global__ __launch_bounds__(256) void cvt_bf16(const float* __restrict__ in,
                                                u16* __restrict__ out, int n8) {
  int i = blockIdx.x * 256 + threadIdx.x;
  if (i >= n8) return;
  const float4* p = (const float4*)in + 2 * (size_t)i;
  float4 a = p[0], b = p[1];
  uint4 o;
  o.x = (unsigned)f2bf(a.x) | ((unsigned)f2bf(a.y) << 16);
  o.y = (unsigned)f2bf(a.z) | ((unsigned)f2bf(a.w) << 16);
  o.z = (unsigned)f2bf(b.x) | ((unsigned)f2bf(b.y) << 16);
  o.w = (unsigned)f2bf(b.z) | ((unsigned)f2bf(b.w) << 16);
  ((uint4*)out)[i] = o;
}

// ------ fused transpose+cvt of ALL weights: one launch, vectorized ------
// in (R x C) f32 -> out (C x R) bf16, 64x64 tiles; block ranges per matrix.
__global__ __launch_bounds__(256) void transpose_all(const float* __restrict__ Wq,
                                                     const float* __restrict__ Wk,
                                                     const float* __restrict__ Wv,
                                                     const float* __restrict__ Wo,
                                                     const float* __restrict__ tWq,
                                                     const float* __restrict__ tWv,
                                                     u16* __restrict__ WqkvT,
                                                     u16* __restrict__ WoT,
                                                     u16* __restrict__ Tt) {
  __shared__ float tile[64][65];
  int b = blockIdx.x;
  const float* in; u16* out; int R, C, bx, by;
  if (b < 1024)      { in = Wq;  out = WqkvT;                R = 2048; C = 2048; bx = b & 31; by = b >> 5; }
  else if (b < 1280) { b -= 1024; in = Wk; out = WqkvT + 2048ull * 2048; R = 2048; C = 512; bx = b & 7; by = b >> 3; }
  else if (b < 1536) { b -= 1280; in = Wv; out = WqkvT + 2560ull * 2048; R = 2048; C = 512; bx = b & 7; by = b >> 3; }
  else if (b < 2560) { b -= 1536; in = Wo; out = WoT;        R = 2048; C = 2048; bx = b & 31; by = b >> 5; }
  else if (b < 2608) { b -= 2560; in = tWq; out = Tt;               R = 3072; C = 32; bx = 0; by = b; }
  else               { b -= 2608; in = tWv; out = Tt + 32ull * 3072; R = 3072; C = 32; bx = 0; by = b; }

  const int t = threadIdx.x;
  const int r0 = by * 64, c0 = bx * 64;
  const int lr = t >> 4, lc4 = (t & 15) * 4;
#pragma unroll
  for (int p = 0; p < 4; ++p) {
    int r = p * 16 + lr;
    float4 v = {0.f, 0.f, 0.f, 0.f};
    if (c0 + lc4 < C) v = *(const float4*)(in + (size_t)(r0 + r) * C + c0 + lc4);
    tile[r][lc4] = v.x; tile[r][lc4 + 1] = v.y;
    tile[r][lc4 + 2] = v.z; tile[r][lc4 + 3] = v.w;
  }
  __syncthreads();
  const int cg = t >> 4, rr4 = (t & 15) * 4;
#pragma unroll
  for (int p = 0; p < 4; ++p) {
    int c = p * 16 + cg;
    if (c0 + c < C) {
      uint2 w;
      w.x = (u32)f2bf(tile[rr4][c])     | ((u32)f2bf(tile[rr4 + 1][c]) << 16);
      w.y = (u32)f2bf(tile[rr4 + 2][c]) | ((u32)f2bf(tile[rr4 + 3][c]) << 16);
      *(uint2*)(out + (size_t)(c0 + c) * R + r0 + rr4) = w;
    }
  }
}

// ---------------- bf16 MFMA GEMM: Cpart[z] = A(MxK) * Bt(NxK)^T over K-chunk z --------
template <int WR, int WC>
__global__ __launch_bounds__(256, 3) void gemm_bt(const u16* __restrict__ A,
                                                  const u16* __restrict__ Bt,
                                                  float* __restrict__ Cpart,
                                                  int M, int N, int K, int kPer) {
  constexpr int BM = WR * 64, BN = WC * 64;
  __shared__ __attribute__((aligned(16))) u16 As[BM * 64];
  __shared__ __attribute__((aligned(16))) u16 Bs[BN * 64];
  const int tid = threadIdx.x, wid = tid >> 6, lane = tid & 63;
  const int l16 = lane & 15, quad = lane >> 4;
  const int wm = (wid % WR) * 64, wn = (wid / WR) * 64;
  const int m0 = blockIdx.y * BM, n0 = blockIdx.x * BN;
  const int kIters = K >> 6;
  const int kStart = blockIdx.z * kPer;
  const int kEnd = (kStart + kPer < kIters) ? (kStart + kPer) : kIters;

  const int lrow = lane >> 3;
  const int swz = (lane & 7) ^ lrow;
  const u16* gAb = A + (size_t)m0 * K + (size_t)swz * 8;
  const u16* gBb = Bt + (size_t)n0 * K + (size_t)swz * 8;
  const int sx = l16 & 7;

  f32x4 acc[4][4] = {};
  for (int kt = kStart; kt < kEnd; ++kt) {
    __syncthreads();
    const u16* gA = gAb + (size_t)kt * 64;
    const u16* gB = gBb + (size_t)kt * 64;
#pragma unroll
    for (int j = 0; j < BM / 32; ++j) {
      int i = wid * (BM / 32) + j;
      gl_lds16(gA + (size_t)(i * 8 + lrow) * K, &As[i * 512]);
    }
#pragma unroll
    for (int j = 0; j < BN / 32; ++j) {
      int i = wid * (BN / 32) + j;
      gl_lds16(gB + (size_t)(i * 8 + lrow) * K, &Bs[i * 512]);
    }
    __syncthreads();
    bf16x8 af[4][2], bfr[4][2];
#pragma unroll
    for (int mt = 0; mt < 4; ++mt)
#pragma unroll
      for (int ks = 0; ks < 2; ++ks)
        af[mt][ks] = *(const bf16x8*)(&As[(wm + mt * 16 + l16) * 64 +
                                          (((ks * 4 + quad) ^ sx) * 8)]);
#pragma unroll
    for (int nt = 0; nt < 4; ++nt)
#pragma unroll
      for (int ks = 0; ks < 2; ++ks)
        bfr[nt][ks] = *(const bf16x8*)(&Bs[(wn + nt * 16 + l16) * 64 +
                                           (((ks * 4 + quad) ^ sx) * 8)]);
#pragma unroll
    for (int mt = 0; mt < 4; ++mt)
#pragma unroll
      for (int nt = 0; nt < 4; ++nt)
#pragma unroll
        for (int ks = 0; ks < 2; ++ks)
          acc[mt][nt] = __builtin_amdgcn_mfma_f32_16x16x32_bf16(
              af[mt][ks], bfr[nt][ks], acc[mt][nt], 0, 0, 0);
  }

  float* C = Cpart + (size_t)blockIdx.z * M * N;
#pragma unroll
  for (int mt = 0; mt < 4; ++mt)
#pragma unroll
    for (int nt = 0; nt < 4; ++nt)
#pragma unroll
      for (int r = 0; r < 4; ++r) {
        int row = m0 + wm + mt * 16 + quad * 4 + r;
        int col = n0 + wn + nt * 16 + l16;
        C[(size_t)row * N + col] = acc[mt][nt][r];
      }
}

// ---------------- reduce kernels (split-K epilogues) ----------------
__global__ __launch_bounds__(256) void reduce_gelu(float* __restrict__ base, int P,
                                                   int n4, u16* __restrict__ gout) {
  int i = blockIdx.x * 256 + threadIdx.x;
  if (i >= n4) return;
  size_t n = (size_t)n4 * 4;
  float4 v = ((const float4*)base)[i];
  for (int p = 1; p < P; ++p) {
    float4 w = ((const float4*)(base + (size_t)p * n))[i];
    v.x += w.x; v.y += w.y; v.z += w.z; v.w += w.w;
  }
  if (P > 1) ((float4*)base)[i] = v;
  uint2 o;
  o.x = (u32)f2bf(geluf(v.x)) | ((u32)f2bf(geluf(v.y)) << 16);
  o.y = (u32)f2bf(geluf(v.z)) | ((u32)f2bf(geluf(v.w)) << 16);
  ((uint2*)gout)[i] = o;
}

__global__ __launch_bounds__(256) void reduce_add(const float* __restrict__ base, int P,
                                                  int n4, float* __restrict__ dst) {
  int i = blockIdx.x * 256 + threadIdx.x;
  if (i >= n4) return;
  size_t n = (size_t)n4 * 4;
  float4 v = ((const float4*)base)[i];
  for (int p = 1; p < P; ++p) {
    float4 w = ((const float4*)(base + (size_t)p * n))[i];
    v.x += w.x; v.y += w.y; v.z += w.z; v.w += w.w;
  }
  ((float4*)dst)[i] = v;
}

__global__ __launch_bounds__(256) void reduce_tanh(const float* __restrict__ base, int P,
                                                   int n, float* __restrict__ tokq,
                                                   float* __restrict__ tokv) {
  int i = blockIdx.x * 256 + threadIdx.x;
  if (i >= n) return;
  float v = base[i];
  for (int p = 1; p < P; ++p) v += base[(size_t)p * n + i];
  float t = tanhf(v);
  int col = i & 63, row = i >> 6;
  if (col < 32) tokq[row * 32 + col] = t;
  else          tokv[row * 32 + (col - 32)] = t;
}

// ---------------- prep: tau scaling + RoPE + layouts for attention ----------------
// Q is pre-scaled by 0.125*log2(e) so flash softmax runs in exp2 domain.
#define QSCALE 0.18033688011112042f
__global__ __launch_bounds__(256) void prep_qkv(const float* __restrict__ qkv,
                                                const float* __restrict__ tokq,
                                                const float* __restrict__ tokv,
                                                const float* __restrict__ alpha,
                                                const float* __restrict__ cosb,
                                                const float* __restrict__ sinb,
                                                const int* __restrict__ pos_ids,
                                                u16* __restrict__ Qb,
                                                u16* __restrict__ Kb,
                                                u16* __restrict__ Vt,
                                                u16* __restrict__ Vb) {
  const int s = blockIdx.x;
  const int tid = threadIdx.x;
  __shared__ float cs[16], sn[16], tq_s[32], tv_s[32];
  if (tid < 16) { cs[tid] = cosb[s * 16 + tid]; sn[tid] = sinb[s * 16 + tid]; }
  if (tid < 32) {
    float p = (float)pos_ids[s] + 1.0f;
    float sig = 1.0f / (1.0f + __expf(-alpha[tid] * logf(p)));
    float taupos = 0.5f + sig;
    tq_s[tid] = (tokq[s * 32 + tid] + taupos) * QSCALE;
    tv_s[tid] = tokv[s * 32 + tid] + taupos;
  }
  __syncthreads();
  const float* row = qkv + (size_t)s * 3072;

  for (int idx = tid; idx < 2048; idx += 256) {
    int h = idx >> 6, d = idx & 63;
    float tq = tq_s[h];
    float v;
    if (d < 32) {
      int i = d >> 1;
      float xr = row[h * 64 + i] * tq, xi = row[h * 64 + 16 + i] * tq;
      v = (d & 1) ? (xr * sn[i] + xi * cs[i]) : (xr * cs[i] - xi * sn[i]);
    } else v = row[h * 64 + d] * tq;
    Qb[((size_t)h * 2048 + s) * 64 + d] = f2bf(v);
  }
  for (int idx = tid; idx < 512; idx += 256) {
    int h = idx >> 6, d = idx & 63;
    const float* kr = row + 2048;
    float v;
    if (d < 32) {
      int i = d >> 1;
      float xr = kr[h * 64 + i], xi = kr[h * 64 + 16 + i];
      v = (d & 1) ? (xr * sn[i] + xi * cs[i]) : (xr * cs[i] - xi * sn[i]);
    } else v = kr[h * 64 + d];
    Kb[((size_t)h * 2048 + s) * 64 + d] = f2bf(v);
  }
  for (int idx = tid; idx < 512; idx += 256) {
    int h = idx >> 6, d = idx & 63;
    float v = row[2560 + h * 64 + d] * tv_s[h];
    u16 b = f2bf(v);
    if (Vb) Vb[((size_t)h * 2048 + s) * 64 + d] = b;
    else    Vt[((size_t)h * 64 + d) * 2048 + s] = b;
  }
}

// ---------------- bf16 transpose Vb[h][s][d] -> Vt[h][d][s] ----------------
__global__ __launch_bounds__(256) void vtrans(const u16* __restrict__ Vb,
                                              u16* __restrict__ Vt) {
  __shared__ u16 t[64][68];
  const int s0 = blockIdx.x * 64, h = blockIdx.y;
  const int tid = threadIdx.x;
  const u16* src = Vb + ((size_t)h * 2048 + s0) * 64;
#pragma unroll
  for (int p = 0; p < 4; ++p) {
    int v = p * 256 + tid;
    int r = v >> 4, c = (v & 15) * 4;
    uint2 w = *(const uint2*)(src + (size_t)r * 64 + c);
    t[r][c] = (u16)(w.x & 0xffff); t[r][c + 1] = (u16)(w.x >> 16);
    t[r][c + 2] = (u16)(w.y & 0xffff); t[r][c + 3] = (u16)(w.y >> 16);
  }
  __syncthreads();
  u16* dst = Vt + (size_t)h * 64 * 2048 + s0;
#pragma unroll
  for (int p = 0; p < 4; ++p) {
    int v = p * 256 + tid;
    int d = v >> 4, s = (v & 15) * 4;
    uint2 w;
    w.x = (u32)t[s][d] | ((u32)t[s + 1][d] << 16);
    w.y = (u32)t[s + 2][d] | ((u32)t[s + 3][d] << 16);
    *(uint2*)(dst + (size_t)d * 2048 + s) = w;
  }
}

// ---------------- flash attention v5: KV-split + transposed softmax ----------------
// Ps layout: row stride 64 u16 (banks repeat per row) + XOR chunk swizzle
// (chunk ^ (q&7)) -> b64 writes 2-way (free), b128 reads at the 8-cycle minimum.
__global__ __launch_bounds__(256, 3) void flash_attn(const u16* __restrict__ Qb,
                                                     const u16* __restrict__ Kb,
                                                     const u16* __restrict__ Vt,
                                                     float* __restrict__ Opart,
                                                     float* __restrict__ ml) {
  __shared__ __attribute__((aligned(16))) u16 KsB[2][4096];
  __shared__ __attribute__((aligned(16))) u16 VsB[2][4096];
  __shared__ __attribute__((aligned(16))) u16 Ps[128 * 64];
  const int e = 50 - blockIdx.x;  // reversed: heaviest (qb=15) first
  const int h = blockIdx.y, kvh = h >> 2;
  // decode e -> (qb, cc): group a (a=0..5) holds qb=3a..3a+2, each with a+1 chunks
  int a = 0;
  while (3 * (a + 1) * (a + 2) / 2 <= e) ++a;
  const int rem = e - 3 * a * (a + 1) / 2;
  const int qb = 3 * a + rem / (a + 1);
  const int cc = rem % (a + 1);
  const int k0 = cc * 6;
  const int kvTend = 2 * qb + 2;
  const int k1 = (k0 + 6 < kvTend) ? (k0 + 6) : kvTend;
  const int pid = h * 51 + e;

  const int tid = threadIdx.x, wid = tid >> 6, lane = tid & 63;
  const int l16 = lane & 15, quad = lane >> 4;
  const int lrow = lane >> 3, swz = (lane & 7) ^ lrow, sx = l16 & 7;

  const int q0 = qb * 128 + wid * 32;
  bf16x8 qf[2][2];
#pragma unroll
  for (int mt = 0; mt < 2; ++mt)
#pragma unroll
    for (int ks = 0; ks < 2; ++ks)
      qf[mt][ks] = *(const bf16x8*)(Qb + ((size_t)h * 2048 + q0 + mt * 16 + l16) * 64 +
                                    ks * 32 + quad * 8);

  f32x4 oacc[2][4] = {};          // O^T frags: [q-half][d-frag], lane q = l16
  float mrun[2] = {-3e38f, -3e38f};
  float lrun[2] = {0.f, 0.f};

  const u16* kgb = Kb + ((size_t)kvh * 2048) * 64;
  const u16* vgb = Vt + (size_t)kvh * 64 * 2048;

#define FA_STAGE(KT, BUF)                                                         \
  {                                                                               \
    const u16* kg_ = kgb + (size_t)(KT)*64 * 64;                                  \
    const u16* vg_ = vgb + (size_t)(KT)*64;                                       \
    _Pragma("unroll") for (int j = 0; j < 2; ++j) {                               \
      int i_ = wid * 2 + j;                                                       \
      gl_lds16(kg_ + (size_t)(i_ * 8 + lrow) * 64 + swz * 8, &KsB[BUF][i_ * 512]);\
      gl_lds16(vg_ + (size_t)(i_ * 8 + lrow) * 2048 + swz * 8, &VsB[BUF][i_ * 512]);\
    }                                                                             \
  }

  FA_STAGE(k0, 0)
  for (int kt = k0; kt < k1; ++kt) {
    const int cur = (kt - k0) & 1;
    __syncthreads();
    if (kt + 1 < k1) FA_STAGE(kt + 1, cur ^ 1)
    const u16* Ks = KsB[cur];
    const u16* Vs = VsB[cur];

    // S^T = K Q^T : sacc[mt][kf], C row = k (quad*4+r+16kf), col = q (l16)
    f32x4 sacc[2][4] = {};
#pragma unroll
    for (int kf = 0; kf < 4; ++kf) {
      bf16x8 a0 = *(const bf16x8*)(Ks + (kf * 16 + l16) * 64 + ((quad ^ sx) << 3));
      bf16x8 a1 = *(const bf16x8*)(Ks + (kf * 16 + l16) * 64 + (((4 + quad) ^ sx) << 3));
      sacc[0][kf] = __builtin_amdgcn_mfma_f32_16x16x32_bf16(a0, qf[0][0], sacc[0][kf], 0, 0, 0);
      sacc[0][kf] = __builtin_amdgcn_mfma_f32_16x16x32_bf16(a1, qf[0][1], sacc[0][kf], 0, 0, 0);
      sacc[1][kf] = __builtin_amdgcn_mfma_f32_16x16x32_bf16(a0, qf[1][0], sacc[1][kf], 0, 0, 0);
      sacc[1][kf] = __builtin_amdgcn_mfma_f32_16x16x32_bf16(a1, qf[1][1], sacc[1][kf], 0, 0, 0);
    }

    const bool msk = (kt >= 2 * qb);  // diagonal tiles only
#pragma unroll
    for (int mt = 0; mt < 2; ++mt) {
      const int qg = q0 + mt * 16 + l16;       // this lane's q (fixed)
      if (msk) {
        const int kb = kt * 64 + quad * 4;
#pragma unroll
        for (int kf = 0; kf < 4; ++kf)
#pragma unroll
          for (int r = 0; r < 4; ++r)
            if (kb + kf * 16 + r > qg) sacc[mt][kf][r] = -1e9f;
      }
      f32x4 m4 = sacc[mt][0];
      m4 = __builtin_elementwise_max(m4, sacc[mt][1]);
      m4 = __builtin_elementwise_max(m4, sacc[mt][2]);
      m4 = __builtin_elementwise_max(m4, sacc[mt][3]);
      float mx = fmaxf(fmaxf(m4[0], m4[1]), fmaxf(m4[2], m4[3]));
      mx = fmaxf(mx, __shfl_xor(mx, 16));
      mx = fmaxf(mx, __shfl_xor(mx, 32));
      float mn = fmaxf(mrun[mt], mx);
      float al = __builtin_amdgcn_exp2f(mrun[mt] - mn);
      mrun[mt] = mn;
      float ps = 0.f;
      const int prow = wid * 32 + mt * 16 + l16;
      u16* prp = Ps + prow * 64 + ((quad & 1) << 2);
      const int pswz = prow & 7;
#pragma unroll
      for (int kf = 0; kf < 4; ++kf) {
        bf16x4 pk;
#pragma unroll
        for (int r = 0; r < 4; ++r) {
          float p = __builtin_amdgcn_exp2f(sacc[mt][kf][r] - mn);
          ps += p;
          pk[r] = (__bf16)p;
        }
        *(bf16x4*)(prp + (((kf * 2 + (quad >> 1)) ^ pswz) << 3)) = pk;
      }
      ps += __shfl_xor(ps, 16);
      ps += __shfl_xor(ps, 32);
      lrun[mt] = lrun[mt] * al + ps;
#pragma unroll
      for (int df = 0; df < 4; ++df) oacc[mt][df] *= al;
    }

    // O^T += V^T P : A = Vs[d][k], B = Ps[q][k] (same-wave LDS write->read)
#pragma unroll
    for (int ks = 0; ks < 2; ++ks) {
      const int q0r = wid * 32 + l16, q1r = q0r + 16;
      bf16x8 b0 = *(const bf16x8*)(Ps + q0r * 64 + (((ks * 4 + quad) ^ (q0r & 7)) << 3));
      bf16x8 b1 = *(const bf16x8*)(Ps + q1r * 64 + (((ks * 4 + quad) ^ (q1r & 7)) << 3));
#pragma unroll
      for (int df = 0; df < 4; ++df) {
        bf16x8 va = *(const bf16x8*)(Vs + (df * 16 + l16) * 64 + (((ks * 4 + quad) ^ sx) << 3));
        oacc[0][df] = __builtin_amdgcn_mfma_f32_16x16x32_bf16(va, b0, oacc[0][df], 0, 0, 0);
        oacc[1][df] = __builtin_amdgcn_mfma_f32_16x16x32_bf16(va, b1, oacc[1][df], 0, 0, 0);
      }
    }
  }
#undef FA_STAGE

  // epilogue: unnormalized partial O (row q, col d; float4 per d-frag) + (m, l)
  float* Op = Opart + (size_t)pid * 128 * 64;
#pragma unroll
  for (int mt = 0; mt < 2; ++mt) {
    const int qrow = wid * 32 + mt * 16 + l16;
#pragma unroll
    for (int df = 0; df < 4; ++df)
      *(f32x4*)(Op + (size_t)qrow * 64 + df * 16 + quad * 4) = oacc[mt][df];
    if (quad == 0) {
      ml[((size_t)pid * 128 + qrow) * 2] = mrun[mt];
      ml[((size_t)pid * 128 + qrow) * 2 + 1] = lrun[mt];
    }
  }
}

// ---------------- combine partials: O = sum(w_c O_c) / sum(w_c l_c) ----------------
__global__ __launch_bounds__(256) void fa_combine(const float* __restrict__ Opart,
                                                  const float* __restrict__ ml,
                                                  u16* __restrict__ Ob) {
  const int qb = blockIdx.x, h = blockIdx.y;
  const int C = (2 * qb + 7) / 6;                  // chunks for this qb
  const int aa = qb / 3, bb = qb % 3;
  const int base = h * 51 + 3 * aa * (aa + 1) / 2 + bb * (aa + 1);
  const int t = threadIdx.x;
#pragma unroll
  for (int u = 0; u < 8; ++u) {
    int unit = u * 256 + t;
    int row = unit >> 4, d4 = unit & 15;
    float mstar = -3e38f;
    for (int c = 0; c < C; ++c)
      mstar = fmaxf(mstar, ml[((size_t)(base + c) * 128 + row) * 2]);
    float4 o = {0.f, 0.f, 0.f, 0.f};
    float lsum = 0.f;
    for (int c = 0; c < C; ++c) {
      const float* mlp = &ml[((size_t)(base + c) * 128 + row) * 2];
      float w = __builtin_amdgcn_exp2f(mlp[0] - mstar);
      float4 v = ((const float4*)(Opart + ((size_t)(base + c) * 128 + row) * 64))[d4];
      o.x += w * v.x; o.y += w * v.y; o.z += w * v.z; o.w += w * v.w;
      lsum += w * mlp[1];
    }
    float inv = 1.0f / lsum;
    uint2 pk;
    pk.x = (u32)f2bf(o.x * inv) | ((u32)f2bf(o.y * inv) << 16);
    pk.y = (u32)f2bf(o.z * inv) | ((u32)f2bf(o.w * inv) << 16);
    *(uint2*)(Ob + (size_t)(qb * 128 + row) * 2048 + h * 64 + d4 * 4) = pk;
  }
}

// ---------------- launcher ----------------
extern "C" void kernel_launch(void* const* d_in, const int* in_sizes, int n_in,
                              void* d_out, int out_size, void* d_ws, size_t ws_size,
                              hipStream_t stream) {
  (void)in_sizes; (void)n_in; (void)out_size;
  const float* hidden = (const float*)d_in[0];
  const float* cosb   = (const float*)d_in[1];
  const float* sinb   = (const float*)d_in[2];
  const int*   pos    = (const int*)d_in[3];
  const float* Wq     = (const float*)d_in[4];
  const float* Wk     = (const float*)d_in[5];
  const float* Wv     = (const float*)d_in[6];
  const float* Wo     = (const float*)d_in[7];
  const float* tWq    = (const float*)d_in[8];
  const float* tWv    = (const float*)d_in[9];
  const float* alpha  = (const float*)d_in[10];
  float* out = (float*)d_out;

  const bool big = ws_size >= (size_t)120 * 1024 * 1024;
  const int Pq = big ? 2 : 1;
  const int Pt = big ? 16 : 1;
  const int Po = big ? 3 : 1;

  char* ws = (char*)d_ws;
  size_t off = 0;
  auto alloc = [&](size_t bytes) -> void* {
    void* p = ws + off;
    off += (bytes + 255) & ~(size_t)255;
    return p;
  };
  u16*   WoT   = (u16*)alloc(2048ull * 2048 * 2);
  u16*   Tt    = (u16*)alloc(64ull * 3072 * 2);
  u16*   Qb    = (u16*)alloc(32ull * 2048 * 64 * 2);
  u16*   Kb    = (u16*)alloc(8ull * 2048 * 64 * 2);
  u16*   Vt    = (u16*)alloc(8ull * 64 * 2048 * 2);
  u16*   Ob    = (u16*)alloc(2048ull * 2048 * 2);
  u16*   featb = (u16*)alloc(2048ull * 3072 * 2);
  float* tokq  = (float*)alloc(2048ull * 32 * 4);
  float* tokv  = (float*)alloc(2048ull * 32 * 4);
  u16*   Vb    = big ? (u16*)alloc(8ull * 2048 * 64 * 2) : nullptr;
  // early region (dead after prep) -> reused for flash partials -> out partials
  size_t E = off;
  u16*   Xb      = (u16*)alloc(2048ull * 2048 * 2);
  u16*   WqkvT   = (u16*)alloc(3072ull * 2048 * 2);
  float* qkvPart = (float*)alloc((size_t)Pq * 2048 * 3072 * 4);
  float* qkv     = qkvPart;
  float* tokPart = (float*)(ws + E);
  float* Opart   = (float*)(ws + E);                           // 1632*128*64*4 = 53.5 MB
  float* mlbuf   = (float*)(ws + E + 1632ull * 128 * 64 * 4);  // +1.7 MB
  float* outPart = (float*)(ws + E);

  cvt_bf16<<<2048, 256, 0, stream>>>(hidden, Xb, 2048 * 2048 / 8);
  transpose_all<<<2656, 256, 0, stream>>>(Wq, Wk, Wv, Wo, tWq, tWv, WqkvT, WoT, Tt);

  gemm_bt<2, 2><<<dim3(24, 16, Pq), 256, 0, stream>>>(
      Xb, WqkvT, qkvPart, 2048, 3072, 2048, (32 + Pq - 1) / Pq);
  reduce_gelu<<<6144, 256, 0, stream>>>(qkvPart, Pq, 2048 * 3072 / 4, featb);

  gemm_bt<4, 1><<<dim3(1, 8, Pt), 256, 0, stream>>>(
      featb, Tt, tokPart, 2048, 64, 3072, (48 + Pt - 1) / Pt);
  reduce_tanh<<<512, 256, 0, stream>>>(tokPart, Pt, 2048 * 64, tokq, tokv);

  prep_qkv<<<2048, 256, 0, stream>>>(qkv, tokq, tokv, alpha, cosb, sinb, pos,
                                     Qb, Kb, Vt, Vb);
  if (big) vtrans<<<dim3(32, 8), 256, 0, stream>>>(Vb, Vt);

  flash_attn<<<dim3(51, 32), 256, 0, stream>>>(Qb, Kb, Vt, Opart, mlbuf);
  fa_combine<<<dim3(16, 32), 256, 0, stream>>>(Opart, mlbuf, Ob);

  gemm_bt<2, 2><<<dim3(16, 16, Po), 256, 0, stream>>>(
      Ob, WoT, outPart, 2048, 2048, 2048, (32 + Po - 1) / Po);
  reduce_add<<<4096, 256, 0, stream>>>(outPart, Po, 2048 * 2048 / 4, out);
}